// Round 10
// baseline (732.367 us; speedup 1.0000x reference)
//
#include <hip/hip_runtime.h>
#include <cmath>

// Problem constants
#define CN   256   // channels (N_DIST)
#define HN   256   // H
#define WN   192   // W
#define KN   129   // kernel taps
#define RN   64    // radius
#define SN   256   // padded size
#define PADN 32    // (SN - WN)/2

// Rotation LDS tile: 64x64 output tile -> rotated source bbox <= 91x91
#define BBR 92
#define BBP 96

// NOTE on __launch_bounds__(block, N) on gfx950/hipcc (measured r3/r5/r6/r7):
// with 512-thr blocks the VGPR cap ~= 256/N  (N=2 -> 128, N=4 -> 64,
// N=6 -> 40). Use N=2 for register-heavy conv kernels.
// r7 lesson: exotic rotating-file variants can spill where a proven schedule
// fits -- change one thing at a time and watch VGPR_Count/WRITE_SIZE.

// ======== conv along W, 256-wide images (round-5/9 proven: 81us, no spill) ====
// Block: 512 thr = 8 waves. Tile: 64 rows x 128 output cols; lane = row,
// wave = 16-col chunk. Stage 64 x 192 REAL cols once (PITCH=196 dwords ->
// b128 lane-stride 4 mod 32 tiles all banks per 8 lanes); 50.7 KB.
// Per-thread window = 18 8-float blocks, 8-slot rotating file X[G&7][8],
// preload 6, prefetch q0/q1/q2/q4 (>=1/2 stage ahead of first use).
// Halo: wave-uniform interior test; clamped-scalar fallback (edge waves only).
template <int TW, int WD, bool ACC>
__global__ __launch_bounds__(512, 2) void conv_w_blk(const float* __restrict__ in,
                                                     const float* __restrict__ kern,
                                                     float* __restrict__ out) {
    constexpr int NO    = TW / 8;          // outputs per thread (16)
    constexpr int TOTB  = (NO + 128) / 8;  // total blocks per thread (18)
    constexpr int PITCH = 196;             // /4 = 49 odd -> b128 conflict-free
    static_assert(NO == 16, "this instantiation is tuned for NO=16");
    __shared__ float lds[64 * PITCH + 132];
    float* __restrict__ ldsK = lds + 64 * PITCH;
    const int tid = threadIdx.x;
    const int x0  = blockIdx.x * TW;
    const int h0  = blockIdx.y * 64;
    const int c   = blockIdx.z;
    const float* __restrict__ in_c = in + ((size_t)c * HN + h0) * WD;

    if (tid < 132) ldsK[tid] = (tid < KN) ? kern[c * KN + tid] : 0.f;

    const int gc0 = max(0, x0 - 64);       // first staged real col (192 staged)
    {   // stage 64 rows x 192 real cols as float4 (conflict-free)
        const int srow = tid >> 3;         // 0..63
        const int scg  = tid & 7;
#pragma unroll
        for (int m = 0; m < 6; ++m) {
            const int c4 = scg + 8 * m;    // 0..47
            *(float4*)(lds + srow * PITCH + 4 * c4) =
                *(const float4*)(in_c + (size_t)srow * WD + gc0 + 4 * c4);
        }
    }
    __syncthreads();

    const int wv  = tid >> 6;              // wave -> 16-col output chunk
    const int l   = tid & 63;              // lane = row
    const int ac0 = x0 + wv * NO - 64;     // abs col of window elem 0 (mult of 8)
    const int lbase = l * PITCH + (ac0 - gc0);

    float acc[NO];
#pragma unroll
    for (int t = 0; t < NO; ++t) acc[t] = 0.f;

    float X[8][8];                         // 8-slot rotating block file

    // guarded 8-float block load; G folds to a constant after unroll
#define RD8(G)                                                                \
    if ((G) < TOTB) {                                                         \
        const int ac_ = ac0 + 8 * (G);                                        \
        if (ac_ >= 0 && ac_ + 8 <= WD) {  /* wave-uniform branch */           \
            const float4 a_ = *(const float4*)(lds + lbase + 8 * (G));        \
            const float4 b_ = *(const float4*)(lds + lbase + 8 * (G) + 4);    \
            X[(G) & 7][0] = a_.x; X[(G) & 7][1] = a_.y;                       \
            X[(G) & 7][2] = a_.z; X[(G) & 7][3] = a_.w;                       \
            X[(G) & 7][4] = b_.x; X[(G) & 7][5] = b_.y;                       \
            X[(G) & 7][6] = b_.z; X[(G) & 7][7] = b_.w;                       \
        } else {                                                              \
            _Pragma("unroll")                                                 \
            for (int i_ = 0; i_ < 8; ++i_) {                                  \
                const int cc_ = ac_ + i_;                                     \
                const int cl_ = min(max(cc_, 0), WD - 1);                     \
                const float v_ = lds[l * PITCH + (cl_ - gc0)];                \
                X[(G) & 7][i_] = (cc_ == cl_) ? v_ : 0.f;                     \
            }                                                                 \
        }                                                                     \
    }

    RD8(0) RD8(1) RD8(2) RD8(3) RD8(4) RD8(5)

    const float4* __restrict__ k4 = (const float4*)ldsK;
#pragma unroll
    for (int s = 0; s < 4; ++s) {          // taps 32s .. 32s+31
        float4 kc = k4[8 * s];
#pragma unroll
        for (int q = 0; q < 8; ++q) {
            float4 kn = (q < 7) ? k4[8 * s + q + 1] : kc;
#pragma unroll
            for (int u = 0; u < 4; ++u) {
                const float kj = (u == 0) ? kc.x : (u == 1) ? kc.y
                               : (u == 2) ? kc.z : kc.w;
#pragma unroll
                for (int t = 0; t < NO; ++t) {
                    const int e = 4 * q + u + t;            // stage-relative
                    acc[t] = fmaf(X[(4 * s + e / 8) & 7][e % 8], kj, acc[t]);
                }
            }
            if (q == 0) { RD8(4 * s + 6) }
            if (q == 1) { RD8(4 * s + 7) }
            if (q == 2) { RD8(4 * s + 8) }
            if (q == 4) { RD8(4 * s + 9) }
            kc = kn;
        }
    }
    {   // tap 128: stage-3-relative e = 32+t -> blocks 16,17 (slots 0,1)
        const float k128 = ldsK[128];
#pragma unroll
        for (int t = 0; t < NO; ++t) {
            const int e = 32 + t;
            acc[t] = fmaf(X[(12 + e / 8) & 7][e % 8], k128, acc[t]);
        }
    }
#undef RD8

    // ---- transpose through LDS (window dead) for coalesced float4 stores ----
    __syncthreads();
#pragma unroll
    for (int i = 0; i < NO; i += 4)
        *(float4*)(lds + l * PITCH + wv * NO + i) =
            make_float4(acc[i], acc[i + 1], acc[i + 2], acc[i + 3]);
    __syncthreads();
    float* __restrict__ obase = out + ((size_t)c * HN + h0) * WD + x0;
    constexpr int NF4 = (64 * TW / 4) / 512;   // 4
#pragma unroll
    for (int k = 0; k < NF4; ++k) {
        const int i4  = k * 512 + tid;
        const int r   = i4 / (TW / 4);
        const int c4o = i4 - r * (TW / 4);
        float4 v = *(const float4*)(lds + r * PITCH + 4 * c4o);
        if (ACC) {
            const float4 o = *(const float4*)(obase + (size_t)r * WD + 4 * c4o);
            v.x += o.x; v.y += o.y; v.z += o.z; v.w += o.w;
        }
        *(float4*)(obase + (size_t)r * WD + 4 * c4o) = v;
    }
}

// ============ conv along W, 192-wide images (round-4 proven, ~55us) ============
// Block: 512 thr = 8 waves. Tile: 64 rows x 96 output cols; NO=12, NB=4
// rolling fresh-read buffers, odd PITCH=225 scalar-read conflict-free,
// zero-filled halo staged in LDS. VGPR 68, no spill.
template <int TW, int WD, bool ACC>
__global__ __launch_bounds__(512, 2) void conv_w_lds(const float* __restrict__ in,
                                                     const float* __restrict__ kern,
                                                     float* __restrict__ out) {
    constexpr int NO    = TW / 8;        // outputs per thread (12)
    constexpr int TWW   = TW + 128;      // window cols
    constexpr int PITCH = TWW + 1;       // odd => conflict-free row-strided reads
    constexpr int NB    = (2 * NO + 31) / NO;  // 4
    __shared__ float lds[64 * PITCH + 132];
    float* __restrict__ ldsK = lds + 64 * PITCH;
    const int tid = threadIdx.x;
    const int x0  = blockIdx.x * TW;
    const int h0  = blockIdx.y * 64;
    const int c   = blockIdx.z;
    const float* __restrict__ in_c = in + ((size_t)c * HN + h0) * WD;

    if (tid < 132) ldsK[tid] = (tid < KN) ? kern[c * KN + tid] : 0.f;

    const int colg = tid & 63;          // staging: lane-coalesced cols
    const int rr   = tid >> 6;          // 0..7; rows rr + 8k
    const int off  = x0 - 64;           // global col of window col 0

    if (off >= 0 && off + TWW <= WD) {  // interior: no bounds code
#pragma unroll
        for (int m = 0; m < 4; ++m) {
            if (colg + 64 * m < TWW) {
#pragma unroll
                for (int k = 0; k < 8; ++k)
                    lds[(rr + 8 * k) * PITCH + colg + 64 * m] =
                        in_c[(size_t)(rr + 8 * k) * WD + off + colg + 64 * m];
            }
        }
    } else {
#pragma unroll
        for (int m = 0; m < 4; ++m) {
            if (colg + 64 * m < TWW) {
#pragma unroll
                for (int k = 0; k < 8; ++k) {
                    int g  = off + colg + 64 * m;
                    int gc = min(max(g, 0), WD - 1);
                    float v = in_c[(size_t)(rr + 8 * k) * WD + gc];
                    lds[(rr + 8 * k) * PITCH + colg + 64 * m] = (g == gc) ? v : 0.f;
                }
            }
        }
    }
    __syncthreads();

    const int wv = tid >> 6;            // wave -> NO-col output chunk
    const int l  = tid & 63;            // lane = row
    const int base = l * PITCH + wv * NO;

    float acc[NO];
#pragma unroll
    for (int t = 0; t < NO; ++t) acc[t] = 0.f;

    float H[4][NO];
    const float4* __restrict__ k4 = (const float4*)ldsK;
#pragma unroll
    for (int s = 0; s < 4; ++s) {
        const int sb = base + 32 * s;
#pragma unroll
        for (int k = 0; k < NB - 1; ++k)
#pragma unroll
            for (int i = 0; i < NO; ++i) H[k][i] = lds[sb + k * NO + i];
        float4 kc = k4[8 * s];
#pragma unroll
        for (int q = 0; q < 8; ++q) {   // 4 taps per q, 32 taps/stage
            float4 kn = (q < 7) ? k4[8 * s + q + 1] : kc;
#pragma unroll
            for (int u = 0; u < 4; ++u) {
                const int up = 4 * q + u;
                const float kj = (u == 0) ? kc.x : (u == 1) ? kc.y
                               : (u == 2) ? kc.z : kc.w;
#pragma unroll
                for (int t = 0; t < NO; ++t) {
                    const int e = up + t;   // compile-time after unroll
                    const float val = (e < NO)     ? H[0][e]
                                    : (e < 2 * NO) ? H[1][e - NO]
                                    : (e < 3 * NO) ? H[2][e - 2 * NO]
                                                   : H[3][e - 3 * NO];
                    acc[t] = fmaf(val, kj, acc[t]);
                }
            }
            if (q == 0) {               // prefetch last buffer: first use q>=4
#pragma unroll
                for (int i = 0; i < NO; ++i)
                    H[NB - 1][i] = lds[sb + (NB - 1) * NO + i];
            }
            kc = kn;
        }
        if (s == 3) {                   // tap 128: stage-3-relative elems 32+t
            const float k128 = ldsK[128];
#pragma unroll
            for (int t = 0; t < NO; ++t) {
                const int e = 32 + t;
                const float val = (e < NO)     ? H[0][e]
                                : (e < 2 * NO) ? H[1][e - NO]
                                : (e < 3 * NO) ? H[2][e - 2 * NO]
                                               : H[3][e - 3 * NO];
                acc[t] = fmaf(val, k128, acc[t]);
            }
        }
    }

    // ---- transpose through LDS (window dead) for coalesced stores ----
    __syncthreads();
#pragma unroll
    for (int i = 0; i < NO; ++i) lds[base + i] = acc[i];
    __syncthreads();
    float* __restrict__ obase = out + ((size_t)c * HN + h0) * WD + x0;
#pragma unroll
    for (int k = 0; k < (64 * TW) / 512; ++k) {
        const int idx = k * 512 + tid;
        const int r  = idx / TW;        // constant divisor -> magic mul
        const int cl = idx - r * TW;
        float v = lds[r * PITCH + cl];
        if (ACC) v += obase[(size_t)r * WD + cl];
        obase[(size_t)r * WD + cl] = v;
    }
}

// ================= conv along H (axis 1), full-height NO=32 =================
// Block: 512 thr = 8 waves; whole column band: 256 output rows x 64 cols.
// Full 256x64 image band staged ONCE as float4 (64 KB -> 2 blocks/CU);
// NO halo staging -- zero rows handled by guarded buffer reads. Wave wv
// computes output rows [wv*32, +32): NO=32, 2-buffer ping-pong (both live
// through each stage; fresh 32-block read between stages). 160 reads /
// 4128 FMAs = 0.039 reads/FMA; HBM fetch redundancy 2x -> 1x vs r9.
// Live floats: 96 buffers+acc + ~16 addr ~= 115 VGPR -> fits (512,2) cap 128.
// (This is the r3 structure; r3's spill was the (512,4) 64-VGPR cap.)
__global__ __launch_bounds__(512, 2) void conv_h_lds(const float* __restrict__ in,
                                                     const float* __restrict__ kern,
                                                     float* __restrict__ out) {
    __shared__ float lds[256 * 64 + 132];
    float* __restrict__ ldsK = lds + 256 * 64;
    const int tid = threadIdx.x;
    const int x0  = blockIdx.x * 64;
    const int c   = blockIdx.y;
    const float* __restrict__ in_c = in + (size_t)c * HN * WN + x0;

    if (tid < 132) ldsK[tid] = (tid < KN) ? kern[c * KN + tid] : 0.f;

    {   // stage full 256 x 64 band, float4 (coalesced, conflict-free b128)
        const int f4 = (tid & 15) * 4;
        const int rw = tid >> 4;        // 0..31; rows rw + 32p
#pragma unroll
        for (int p = 0; p < 8; ++p) {
            const int r = rw + 32 * p;
            *(float4*)(lds + r * 64 + f4) =
                *(const float4*)(in_c + (size_t)r * WN + f4);
        }
    }
    __syncthreads();

    const int wv = tid >> 6;            // wave -> output rows [wv*32, +32)
    const int l  = tid & 63;            // lane = col
    const int rbase = wv * 32 - 64;     // input row of window element 0

    float acc[32];
#pragma unroll
    for (int t = 0; t < 32; ++t) acc[t] = 0.f;

    float B0[32], B1[32];

    // guarded 32-row block read: rows rf..rf+31 (OOB -> 0); wave-uniform branch
#define RDBLK(BUF, rfirst)                                                    \
    {                                                                         \
        const int rf = (rfirst);                                              \
        if (rf >= 0 && rf + 31 < HN) {                                        \
            _Pragma("unroll")                                                 \
            for (int i = 0; i < 32; ++i) BUF[i] = lds[(rf + i) * 64 + l];     \
        } else {                                                              \
            _Pragma("unroll")                                                 \
            for (int i = 0; i < 32; ++i) {                                    \
                const int r  = rf + i;                                        \
                const int rc = min(max(r, 0), HN - 1);                        \
                const float v = lds[rc * 64 + l];                             \
                BUF[i] = (r == rc) ? v : 0.f;                                 \
            }                                                                 \
        }                                                                     \
    }

#define STAGE(s, LOW, HIGH)                                                   \
    {                                                                         \
        const float4* __restrict__ k4 = (const float4*)ldsK;                  \
        float4 kc = k4[8 * (s)];                                              \
        _Pragma("unroll")                                                     \
        for (int q = 0; q < 8; ++q) {                                         \
            float4 kn = (q < 7) ? k4[8 * (s) + q + 1] : kc;                   \
            _Pragma("unroll")                                                 \
            for (int u = 0; u < 4; ++u) {                                     \
                const float kj = (u == 0) ? kc.x : (u == 1) ? kc.y            \
                               : (u == 2) ? kc.z : kc.w;                      \
                _Pragma("unroll")                                             \
                for (int t = 0; t < 32; ++t) {                                \
                    const int e = 4 * q + u + t;                              \
                    const float val = (e < 32) ? LOW[e] : HIGH[e - 32];       \
                    acc[t] = fmaf(val, kj, acc[t]);                           \
                }                                                             \
            }                                                                 \
            kc = kn;                                                          \
        }                                                                     \
    }

    RDBLK(B0, rbase);
    RDBLK(B1, rbase + 32);
    STAGE(0, B0, B1);
    RDBLK(B0, rbase + 64);
    STAGE(1, B1, B0);
    RDBLK(B1, rbase + 96);
    STAGE(2, B0, B1);
    RDBLK(B0, rbase + 128);
    STAGE(3, B1, B0);
    {   // tap 128: input rows rbase+128+t == B0 exactly
        const float k128 = ldsK[128];
#pragma unroll
        for (int t = 0; t < 32; ++t) acc[t] = fmaf(B0[t], k128, acc[t]);
    }
#undef RDBLK
#undef STAGE

    float* __restrict__ ob = out + ((size_t)c * HN + wv * 32) * WN + x0 + l;
#pragma unroll
    for (int t = 0; t < 32; ++t) ob[(size_t)t * WN] = acc[t];
}

// ---------------- forward rotate via LDS tile ----------------
__global__ __launch_bounds__(256) void rot_fwd_lds(const float* __restrict__ Cin,
                                                   float* __restrict__ out,
                                                   float ca, float sa) {
    __shared__ float tile[BBR * BBP];
    const int j0 = blockIdx.x * 64;
    const int i0 = blockIdx.y * 64;
    const int c  = blockIdx.z;
    const float cc = (SN - 1) * 0.5f;               // 127.5
    const float yA = (float)i0 - cc, yB = (float)(i0 + 63) - cc;
    const float xA = (float)j0 - cc, xB = (float)(j0 + 63) - cc;
    const float syAA = ca * yA + sa * xA + cc, syAB = ca * yA + sa * xB + cc;
    const float syBA = ca * yB + sa * xA + cc, syBB = ca * yB + sa * xB + cc;
    const float sxAA = -sa * yA + ca * xA + cc, sxAB = -sa * yA + ca * xB + cc;
    const float sxBA = -sa * yB + ca * xA + cc, sxBB = -sa * yB + ca * xB + cc;
    const int ybase = (int)floorf(fminf(fminf(syAA, syAB), fminf(syBA, syBB))) - 1;
    const int xbase = (int)floorf(fminf(fminf(sxAA, sxAB), fminf(sxBA, sxBB))) - 1;

    const float* __restrict__ base = Cin + (size_t)c * HN * WN;
    for (int t = threadIdx.x; t < BBR * BBP; t += 256) {
        const int r  = t / BBP;
        const int q  = t - r * BBP;
        const int gy = ybase + r;           // padded-space row == C row
        const int gx = xbase + q - PADN;    // col into C (implicit zero pad)
        float v = 0.f;
        if ((unsigned)gy < (unsigned)HN && (unsigned)gx < (unsigned)WN)
            v = base[(size_t)gy * WN + gx];
        tile[t] = v;
    }
    __syncthreads();

    const int l  = threadIdx.x & 63;        // col within tile (lane)
    const int r0 = threadIdx.x >> 6;        // wave -> row phase
    const int j  = j0 + l;
    const float xx = (float)j - cc;
    float* __restrict__ ocol = out + (size_t)c * SN * SN + j;
#pragma unroll
    for (int t = 0; t < 16; ++t) {
        const int i = i0 + r0 + 4 * t;
        const float yy = (float)i - cc;
        const float sy = ca * yy + sa * xx + cc;
        const float sx = -sa * yy + ca * xx + cc;
        const float y0f = floorf(sy), x0f = floorf(sx);
        const float fy = sy - y0f, fx = sx - x0f;
        const int ly = (int)y0f - ybase;
        const int lx = (int)x0f - xbase;
        const float* p = tile + ly * BBP + lx;
        const float v00 = p[0], v01 = p[1], v10 = p[BBP], v11 = p[BBP + 1];
        ocol[(size_t)i * SN] = (1.f - fy) * ((1.f - fx) * v00 + fx * v01)
                             + fy * ((1.f - fx) * v10 + fx * v11);
    }
}

// ---------------- inverse rotate via LDS tile (+ optional fused finalize) ----
template <bool FINAL>
__global__ __launch_bounds__(256) void rot_bwd_lds(const float* __restrict__ U,
                                                   float* __restrict__ dst,
                                                   const float* __restrict__ accIn,
                                                   const float* __restrict__ norm,
                                                   float ca, float sa) {
    __shared__ float tile[BBR * BBP];
    const int x0 = blockIdx.x * 64;
    const int i0 = blockIdx.y * 64;
    const int c  = blockIdx.z;
    const float cc = (SN - 1) * 0.5f;
    const float yA = (float)i0 - cc, yB = (float)(i0 + 63) - cc;
    const float xA = (float)(x0 + PADN) - cc, xB = (float)(x0 + PADN + 63) - cc;
    const float syAA = ca * yA + sa * xA + cc, syAB = ca * yA + sa * xB + cc;
    const float syBA = ca * yB + sa * xA + cc, syBB = ca * yB + sa * xB + cc;
    const float sxAA = -sa * yA + ca * xA + cc, sxAB = -sa * yA + ca * xB + cc;
    const float sxBA = -sa * yB + ca * xA + cc, sxBB = -sa * yB + ca * xB + cc;
    const int ybase = (int)floorf(fminf(fminf(syAA, syAB), fminf(syBA, syBB))) - 1;
    const int xbase = (int)floorf(fminf(fminf(sxAA, sxAB), fminf(sxBA, sxBB))) - 1;

    const float* __restrict__ base = U + (size_t)c * SN * SN;
    for (int t = threadIdx.x; t < BBR * BBP; t += 256) {
        const int r  = t / BBP;
        const int q  = t - r * BBP;
        const int gy = ybase + r;
        const int gx = xbase + q;
        float v = 0.f;
        if ((unsigned)gy < (unsigned)SN && (unsigned)gx < (unsigned)SN)
            v = base[(size_t)gy * SN + gx];
        tile[t] = v;
    }
    __syncthreads();

    const int l  = threadIdx.x & 63;
    const int r0 = threadIdx.x >> 6;
    const int xc = x0 + l;
    const float xx = (float)(xc + PADN) - cc;
    float inv = 0.f;
    if constexpr (FINAL) inv = 1.f / norm[c];
#pragma unroll
    for (int t = 0; t < 16; ++t) {
        const int i = i0 + r0 + 4 * t;
        const float yy = (float)i - cc;
        const float sy = ca * yy + sa * xx + cc;
        const float sx = -sa * yy + ca * xx + cc;
        const float y0f = floorf(sy), x0f = floorf(sx);
        const float fy = sy - y0f, fx = sx - x0f;
        const int ly = (int)y0f - ybase;
        const int lx = (int)x0f - xbase;
        const float* p = tile + ly * BBP + lx;
        const float v00 = p[0], v01 = p[1], v10 = p[BBP], v11 = p[BBP + 1];
        const float val = (1.f - fy) * ((1.f - fx) * v00 + fx * v01)
                        + fy * ((1.f - fx) * v10 + fx * v11);
        const size_t idx = ((size_t)c * HN + i) * WN + xc;
        if constexpr (FINAL) {
            dst[idx] = (dst[idx] + accIn[idx] + val) * inv;
        } else {
            dst[idx] += val;
        }
    }
}

extern "C" void kernel_launch(void* const* d_in, const int* in_sizes, int n_in,
                              void* d_out, int out_size, void* d_ws, size_t ws_size,
                              hipStream_t stream) {
    const float* x    = (const float*)d_in[0];
    const float* kg   = (const float*)d_in[1];
    const float* kw   = (const float*)d_in[2];
    const float* kiso = (const float*)d_in[3];
    const float* norm = (const float*)d_in[4];

    float* C = (float*)d_out;                 // 256*256*192 floats
    float* ws = (float*)d_ws;
    const size_t IMG = (size_t)CN * HN * WN;  // 12,582,912
    const size_t PSQ = (size_t)CN * SN * SN;  // 16,777,216
    float* B   = ws;                          // IMG
    float* acc = ws + IMG;                    // IMG
    float* T   = ws + 2 * IMG;                // PSQ
    float* U   = T + PSQ;                     // PSQ

    const dim3 blk256(256);
    const dim3 blk512(512);
    const dim3 convHGrid(WN / 64, CN);            // 3 x 256, full-height bands
    const dim3 convW192Grid(2, HN / 64, CN);      // TW=96
    const dim3 convW256Grid(2, HN / 64, CN);      // TW=128
    const dim3 rotFGrid(SN / 64, SN / 64, CN);    // 4 x 4 x 256
    const dim3 rotBGrid(WN / 64, HN / 64, CN);    // 3 x 4 x 256

    // 1-2: gaussian separable conv -> C (d_out)
    conv_h_lds<<<convHGrid, blk512, 0, stream>>>(x, kg, B);
    conv_w_lds<96, WN, false><<<convW192Grid, blk512, 0, stream>>>(B, kg, C);
    // 3-4: iso separable conv -> acc
    conv_h_lds<<<convHGrid, blk512, 0, stream>>>(C, kiso, B);
    conv_w_lds<96, WN, false><<<convW192Grid, blk512, 0, stream>>>(B, kiso, acc);
    // 5: i=0 tail term (identity rotation): acc += conv_w(C, kw)
    conv_w_lds<96, WN, true><<<convW192Grid, blk512, 0, stream>>>(C, kw, acc);
    // 6-11: i=1,2 tail terms
    const double a1 = 60.0 * M_PI / 180.0, a2 = 120.0 * M_PI / 180.0;
    const float c1 = (float)cos(a1), s1 = (float)sin(a1);
    const float c2 = (float)cos(a2), s2 = (float)sin(a2);

    rot_fwd_lds<<<rotFGrid, blk256, 0, stream>>>(C, T, c1, s1);
    conv_w_blk<128, SN, false><<<convW256Grid, blk512, 0, stream>>>(T, kw, U);
    rot_bwd_lds<false><<<rotBGrid, blk256, 0, stream>>>(U, acc, nullptr, nullptr, c1, -s1);

    rot_fwd_lds<<<rotFGrid, blk256, 0, stream>>>(C, T, c2, s2);
    conv_w_blk<128, SN, false><<<convW256Grid, blk512, 0, stream>>>(T, kw, U);
    // 12 fused: out = (C + acc + tail2) / norm[c]
    rot_bwd_lds<true><<<rotBGrid, blk256, 0, stream>>>(U, C, acc, norm, c2, -s2);

    (void)in_sizes; (void)n_in; (void)out_size; (void)ws_size;
}

// Round 12
// 662.187 us; speedup vs baseline: 1.1060x; 1.1060x over previous
//
#include <hip/hip_runtime.h>
#include <cmath>

// Problem constants
#define CN   256   // channels (N_DIST)
#define HN   256   // H
#define WN   192   // W
#define KN   129   // kernel taps
#define RN   64    // radius
#define SN   256   // padded size
#define PADN 32    // (SN - WN)/2

// Rotation LDS tile: 64x64 output tile -> rotated source bbox <= 91x91
#define BBR 92
#define BBP 96

// NOTE on __launch_bounds__(block, N) on gfx950/hipcc (measured r3/r5/r6/r7):
// with 512-thr blocks the VGPR cap ~= 256/N  (N=2 -> 128, N=4 -> 64,
// N=6 -> 40). Use N=2 for register-heavy conv kernels.
// r10 lesson: conv_h full-height (768-block grid) regressed -- tail effect at
// 2 blocks/CU x 256 CU = 512 slots. Keep grids >= ~1500 blocks.

// ============== conv along W, unified TW=96/128 (zero-padded window) ==========
// Block: 512 thr = 8 waves. Tile: 64 rows x TW output cols; lane = row,
// wave = NO-col chunk (NO = TW/8 = 12 or 16). Stage the FULL TWW=TW+128-col
// window with OOB cols pre-zeroed (r4-style) -> every block read is an
// unconditional 2x ds_read_b128: no clamp VALU, no scalar fallback, no bank
// conflicts (r9's 1.88M conflict cycles were the edge-wave clamped-b32 path).
// PITCH = TWW+4 (PITCH/4 odd -> b128 lane-stride odd mod 32, conflict-free).
// Per-thread window = 18 8-float blocks, 8-slot rotating file X[G&7][8],
// preload 6, prefetch q0/q1/q2/q4 (r5/r9-PROVEN schedule, kept verbatim;
// slot-lifetime audited for NO=12: block 4s frees after q1, 4s+1 after q3).
// Stores transposed through LDS for coalesced float4 writes.
template <int TW, int WD, bool ACC>
__global__ __launch_bounds__(512, 2) void conv_w_blk(const float* __restrict__ in,
                                                     const float* __restrict__ kern,
                                                     float* __restrict__ out) {
    constexpr int NO    = TW / 8;          // 12 or 16
    constexpr int TWW   = TW + 128;        // 224 or 256
    constexpr int PITCH = TWW + 4;         // 228 or 260
    constexpr int TOTB  = (NO + 128 + 7) / 8;  // 18 blocks per thread
    static_assert((PITCH / 4) % 2 == 1, "PITCH/4 must be odd for b128");
    static_assert(NO == 12 || NO == 16, "NO+32 must fit 6 blocks");
    __shared__ float lds[64 * PITCH + 132];
    float* __restrict__ ldsK = lds + 64 * PITCH;
    const int tid = threadIdx.x;
    const int x0  = blockIdx.x * TW;
    const int h0  = blockIdx.y * 64;
    const int c   = blockIdx.z;
    const float* __restrict__ in_c = in + ((size_t)c * HN + h0) * WD;

    if (tid < 132) ldsK[tid] = (tid < KN) ? kern[c * KN + tid] : 0.f;

    const int off = x0 - 64;               // global col of window col 0 (mult 4)
    {   // stage 64 rows x TWW cols as float4, OOB cols zero-filled
        const int srow = tid >> 3;         // 0..63
        const int sc   = tid & 7;
#pragma unroll
        for (int m = 0; m < TWW / 32; ++m) {
            const int c4 = sc + 8 * m;     // float4 col 0..TWW/4-1
            const int g0 = off + 4 * c4;
            float4 v;
            if (g0 >= 0 && g0 + 4 <= WD)   // all-or-nothing (off,WD mult of 4)
                v = *(const float4*)(in_c + (size_t)srow * WD + g0);
            else { v.x = 0.f; v.y = 0.f; v.z = 0.f; v.w = 0.f; }
            *(float4*)(lds + srow * PITCH + 4 * c4) = v;
        }
    }
    __syncthreads();

    const int wv = tid >> 6;               // wave -> NO-col output chunk
    const int l  = tid & 63;               // lane = row
    const int lbase = l * PITCH + wv * NO; // window elem 0 (mult of 4)

    float acc[NO];
#pragma unroll
    for (int t = 0; t < NO; ++t) acc[t] = 0.f;

    float X[8][8];                         // 8-slot rotating block file

    // unconditional 8-float block load (2x ds_read_b128)
#define RD8(G)                                                                \
    if ((G) < TOTB) {                                                         \
        const float4 a_ = *(const float4*)(lds + lbase + 8 * (G));            \
        const float4 b_ = *(const float4*)(lds + lbase + 8 * (G) + 4);        \
        X[(G) & 7][0] = a_.x; X[(G) & 7][1] = a_.y;                           \
        X[(G) & 7][2] = a_.z; X[(G) & 7][3] = a_.w;                           \
        X[(G) & 7][4] = b_.x; X[(G) & 7][5] = b_.y;                           \
        X[(G) & 7][6] = b_.z; X[(G) & 7][7] = b_.w;                           \
    }

    RD8(0) RD8(1) RD8(2) RD8(3) RD8(4) RD8(5)

    const float4* __restrict__ k4 = (const float4*)ldsK;
#pragma unroll
    for (int s = 0; s < 4; ++s) {          // taps 32s .. 32s+31
        float4 kc = k4[8 * s];
#pragma unroll
        for (int q = 0; q < 8; ++q) {
            float4 kn = (q < 7) ? k4[8 * s + q + 1] : kc;
#pragma unroll
            for (int u = 0; u < 4; ++u) {
                const float kj = (u == 0) ? kc.x : (u == 1) ? kc.y
                               : (u == 2) ? kc.z : kc.w;
#pragma unroll
                for (int t = 0; t < NO; ++t) {
                    const int e = 4 * q + u + t;            // stage-relative
                    acc[t] = fmaf(X[(4 * s + e / 8) & 7][e % 8], kj, acc[t]);
                }
            }
            if (q == 0) { RD8(4 * s + 6) }
            if (q == 1) { RD8(4 * s + 7) }
            if (q == 2) { RD8(4 * s + 8) }
            if (q == 4) { RD8(4 * s + 9) }
            kc = kn;
        }
    }
    {   // tap 128: stage-3-relative e = 32+t -> blocks 16,17 (slots 0,1)
        const float k128 = ldsK[128];
#pragma unroll
        for (int t = 0; t < NO; ++t) {
            const int e = 32 + t;
            acc[t] = fmaf(X[(12 + e / 8) & 7][e % 8], k128, acc[t]);
        }
    }
#undef RD8

    // ---- transpose through LDS (window dead) for coalesced float4 stores ----
    __syncthreads();
#pragma unroll
    for (int i = 0; i < NO; i += 4)
        *(float4*)(lds + l * PITCH + wv * NO + i) =
            make_float4(acc[i], acc[i + 1], acc[i + 2], acc[i + 3]);
    __syncthreads();
    float* __restrict__ obase = out + ((size_t)c * HN + h0) * WD + x0;
    constexpr int NF4 = (64 * TW / 4) / 512;   // 3 (TW=96) or 4 (TW=128)
#pragma unroll
    for (int k = 0; k < NF4; ++k) {
        const int i4  = k * 512 + tid;
        const int r   = i4 / (TW / 4);     // const divisor -> magic mul
        const int c4o = i4 - r * (TW / 4);
        float4 v = *(const float4*)(lds + r * PITCH + 4 * c4o);
        if (ACC) {
            const float4 o = *(const float4*)(obase + (size_t)r * WD + 4 * c4o);
            v.x += o.x; v.y += o.y; v.z += o.z; v.w += o.w;
        }
        *(float4*)(obase + (size_t)r * WD + 4 * c4o) = v;
    }
}

// ================= conv along H (axis 1), carried-block LDS =================
// (round-4/9 proven, ~60us; r10's full-height NO=32 regressed -- tail effect)
__global__ __launch_bounds__(512, 2) void conv_h_lds(const float* __restrict__ in,
                                                     const float* __restrict__ kern,
                                                     float* __restrict__ out) {
    __shared__ float lds[256 * 64 + 132];
    float* __restrict__ ldsK = lds + 256 * 64;
    const int tid = threadIdx.x;
    const int x0  = blockIdx.x * 64;
    const int h0  = blockIdx.y * 128;
    const int c   = blockIdx.z;
    const float* __restrict__ in_c = in + (size_t)c * HN * WN + x0;

    if (tid < 132) ldsK[tid] = (tid < KN) ? kern[c * KN + tid] : 0.f;

    {   // stage rows [h0-64, h0+192) x 64 cols, float4, zero-guarded rows
        const int f4 = (tid & 15) * 4;
        const int rw = tid >> 4;            // 0..31; rows rw + 32p
        const int off = h0 - 64;
#pragma unroll
        for (int p = 0; p < 8; ++p) {
            const int lr = rw + 32 * p;
            const int g  = off + lr;
            const int gc = min(max(g, 0), HN - 1);
            float4 v = *(const float4*)(in_c + (size_t)gc * WN + f4);
            if (g != gc) { v.x = 0.f; v.y = 0.f; v.z = 0.f; v.w = 0.f; }
            *(float4*)(lds + lr * 64 + f4) = v;
        }
    }
    __syncthreads();

    const int W = (tid >> 6) * 16;      // wave's window base row
    const int l = tid & 63;             // lane = col

    float acc[16];
#pragma unroll
    for (int t = 0; t < 16; ++t) acc[t] = 0.f;

    float X0[16], X1[16], X2[16], X3[16];

#define RD16(BUF, b)                                                          \
    { _Pragma("unroll")                                                       \
      for (int i = 0; i < 16; ++i) BUF[i] = lds[(W + 16 * (b) + i) * 64 + l]; }

#define STG(s, LOW, MID, HIGH, NXT, hasNxt)                                   \
    {                                                                         \
        const float4* __restrict__ k4 = (const float4*)ldsK;                  \
        float4 kc = k4[8 * (s)];                                              \
        _Pragma("unroll")                                                     \
        for (int q = 0; q < 8; ++q) {                                         \
            float4 kn = (q < 7) ? k4[8 * (s) + q + 1] : kc;                   \
            _Pragma("unroll")                                                 \
            for (int u = 0; u < 4; ++u) {                                     \
                const float kj = (u == 0) ? kc.x : (u == 1) ? kc.y            \
                               : (u == 2) ? kc.z : kc.w;                      \
                _Pragma("unroll")                                             \
                for (int t = 0; t < 16; ++t) {                                \
                    const int e = 4 * q + u + t;                              \
                    const float val = (e < 16) ? LOW[e]                       \
                                    : (e < 32) ? MID[e - 16] : HIGH[e - 32];  \
                    acc[t] = fmaf(val, kj, acc[t]);                           \
                }                                                             \
            }                                                                 \
            if (q == 0) RD16(HIGH, 2 * (s) + 2)                               \
            if ((hasNxt) && q == 1) RD16(NXT, 2 * (s) + 3)                    \
            kc = kn;                                                          \
        }                                                                     \
    }

    RD16(X0, 0)
    RD16(X1, 1)
    STG(0, X0, X1, X2, X3, true)
    STG(1, X2, X3, X0, X1, true)
    STG(2, X0, X1, X2, X3, true)
    STG(3, X2, X3, X0, X1, false)
#undef RD16
#undef STG

    {   // tap 128: block 8 == X0 exactly
        const float k128 = ldsK[128];
#pragma unroll
        for (int t = 0; t < 16; ++t) acc[t] = fmaf(X0[t], k128, acc[t]);
    }

    float* __restrict__ ob = out + ((size_t)c * HN + h0 + W) * WN + x0 + l;
#pragma unroll
    for (int t = 0; t < 16; ++t) ob[(size_t)t * WN] = acc[t];
}

// ---------------- forward rotate via LDS tile ----------------
__global__ __launch_bounds__(256) void rot_fwd_lds(const float* __restrict__ Cin,
                                                   float* __restrict__ out,
                                                   float ca, float sa) {
    __shared__ float tile[BBR * BBP];
    const int j0 = blockIdx.x * 64;
    const int i0 = blockIdx.y * 64;
    const int c  = blockIdx.z;
    const float cc = (SN - 1) * 0.5f;               // 127.5
    const float yA = (float)i0 - cc, yB = (float)(i0 + 63) - cc;
    const float xA = (float)j0 - cc, xB = (float)(j0 + 63) - cc;
    const float syAA = ca * yA + sa * xA + cc, syAB = ca * yA + sa * xB + cc;
    const float syBA = ca * yB + sa * xA + cc, syBB = ca * yB + sa * xB + cc;
    const float sxAA = -sa * yA + ca * xA + cc, sxAB = -sa * yA + ca * xB + cc;
    const float sxBA = -sa * yB + ca * xA + cc, sxBB = -sa * yB + ca * xB + cc;
    const int ybase = (int)floorf(fminf(fminf(syAA, syAB), fminf(syBA, syBB))) - 1;
    const int xbase = (int)floorf(fminf(fminf(sxAA, sxAB), fminf(sxBA, sxBB))) - 1;

    const float* __restrict__ base = Cin + (size_t)c * HN * WN;
    for (int t = threadIdx.x; t < BBR * BBP; t += 256) {
        const int r  = t / BBP;
        const int q  = t - r * BBP;
        const int gy = ybase + r;           // padded-space row == C row
        const int gx = xbase + q - PADN;    // col into C (implicit zero pad)
        float v = 0.f;
        if ((unsigned)gy < (unsigned)HN && (unsigned)gx < (unsigned)WN)
            v = base[(size_t)gy * WN + gx];
        tile[t] = v;
    }
    __syncthreads();

    const int l  = threadIdx.x & 63;        // col within tile (lane)
    const int r0 = threadIdx.x >> 6;        // wave -> row phase
    const int j  = j0 + l;
    const float xx = (float)j - cc;
    float* __restrict__ ocol = out + (size_t)c * SN * SN + j;
#pragma unroll
    for (int t = 0; t < 16; ++t) {
        const int i = i0 + r0 + 4 * t;
        const float yy = (float)i - cc;
        const float sy = ca * yy + sa * xx + cc;
        const float sx = -sa * yy + ca * xx + cc;
        const float y0f = floorf(sy), x0f = floorf(sx);
        const float fy = sy - y0f, fx = sx - x0f;
        const int ly = (int)y0f - ybase;
        const int lx = (int)x0f - xbase;
        const float* p = tile + ly * BBP + lx;
        const float v00 = p[0], v01 = p[1], v10 = p[BBP], v11 = p[BBP + 1];
        ocol[(size_t)i * SN] = (1.f - fy) * ((1.f - fx) * v00 + fx * v01)
                             + fy * ((1.f - fx) * v10 + fx * v11);
    }
}

// ---------------- inverse rotate via LDS tile (+ optional fused finalize) ----
template <bool FINAL>
__global__ __launch_bounds__(256) void rot_bwd_lds(const float* __restrict__ U,
                                                   float* __restrict__ dst,
                                                   const float* __restrict__ accIn,
                                                   const float* __restrict__ norm,
                                                   float ca, float sa) {
    __shared__ float tile[BBR * BBP];
    const int x0 = blockIdx.x * 64;
    const int i0 = blockIdx.y * 64;
    const int c  = blockIdx.z;
    const float cc = (SN - 1) * 0.5f;
    const float yA = (float)i0 - cc, yB = (float)(i0 + 63) - cc;
    const float xA = (float)(x0 + PADN) - cc, xB = (float)(x0 + PADN + 63) - cc;
    const float syAA = ca * yA + sa * xA + cc, syAB = ca * yA + sa * xB + cc;
    const float syBA = ca * yB + sa * xA + cc, syBB = ca * yB + sa * xB + cc;
    const float sxAA = -sa * yA + ca * xA + cc, sxAB = -sa * yA + ca * xB + cc;
    const float sxBA = -sa * yB + ca * xA + cc, sxBB = -sa * yB + ca * xB + cc;
    const int ybase = (int)floorf(fminf(fminf(syAA, syAB), fminf(syBA, syBB))) - 1;
    const int xbase = (int)floorf(fminf(fminf(sxAA, sxAB), fminf(sxBA, sxBB))) - 1;

    const float* __restrict__ base = U + (size_t)c * SN * SN;
    for (int t = threadIdx.x; t < BBR * BBP; t += 256) {
        const int r  = t / BBP;
        const int q  = t - r * BBP;
        const int gy = ybase + r;
        const int gx = xbase + q;
        float v = 0.f;
        if ((unsigned)gy < (unsigned)SN && (unsigned)gx < (unsigned)SN)
            v = base[(size_t)gy * SN + gx];
        tile[t] = v;
    }
    __syncthreads();

    const int l  = threadIdx.x & 63;
    const int r0 = threadIdx.x >> 6;
    const int xc = x0 + l;
    const float xx = (float)(xc + PADN) - cc;
    float inv = 0.f;
    if constexpr (FINAL) inv = 1.f / norm[c];
#pragma unroll
    for (int t = 0; t < 16; ++t) {
        const int i = i0 + r0 + 4 * t;
        const float yy = (float)i - cc;
        const float sy = ca * yy + sa * xx + cc;
        const float sx = -sa * yy + ca * xx + cc;
        const float y0f = floorf(sy), x0f = floorf(sx);
        const float fy = sy - y0f, fx = sx - x0f;
        const int ly = (int)y0f - ybase;
        const int lx = (int)x0f - xbase;
        const float* p = tile + ly * BBP + lx;
        const float v00 = p[0], v01 = p[1], v10 = p[BBP], v11 = p[BBP + 1];
        const float val = (1.f - fy) * ((1.f - fx) * v00 + fx * v01)
                        + fy * ((1.f - fx) * v10 + fx * v11);
        const size_t idx = ((size_t)c * HN + i) * WN + xc;
        if constexpr (FINAL) {
            dst[idx] = (dst[idx] + accIn[idx] + val) * inv;
        } else {
            dst[idx] += val;
        }
    }
}

extern "C" void kernel_launch(void* const* d_in, const int* in_sizes, int n_in,
                              void* d_out, int out_size, void* d_ws, size_t ws_size,
                              hipStream_t stream) {
    const float* x    = (const float*)d_in[0];
    const float* kg   = (const float*)d_in[1];
    const float* kw   = (const float*)d_in[2];
    const float* kiso = (const float*)d_in[3];
    const float* norm = (const float*)d_in[4];

    float* C = (float*)d_out;                 // 256*256*192 floats
    float* ws = (float*)d_ws;
    const size_t IMG = (size_t)CN * HN * WN;  // 12,582,912
    const size_t PSQ = (size_t)CN * SN * SN;  // 16,777,216
    float* B   = ws;                          // IMG
    float* acc = ws + IMG;                    // IMG
    float* T   = ws + 2 * IMG;                // PSQ
    float* U   = T + PSQ;                     // PSQ

    const dim3 blk256(256);
    const dim3 blk512(512);
    const dim3 convHGrid(WN / 64, HN / 128, CN);  // 3 x 2 x 256
    const dim3 convW192Grid(2, HN / 64, CN);      // TW=96
    const dim3 convW256Grid(2, HN / 64, CN);      // TW=128
    const dim3 rotFGrid(SN / 64, SN / 64, CN);    // 4 x 4 x 256
    const dim3 rotBGrid(WN / 64, HN / 64, CN);    // 3 x 4 x 256

    // 1-2: gaussian separable conv -> C (d_out)
    conv_h_lds<<<convHGrid, blk512, 0, stream>>>(x, kg, B);
    conv_w_blk<96, WN, false><<<convW192Grid, blk512, 0, stream>>>(B, kg, C);
    // 3-4: iso separable conv -> acc
    conv_h_lds<<<convHGrid, blk512, 0, stream>>>(C, kiso, B);
    conv_w_blk<96, WN, false><<<convW192Grid, blk512, 0, stream>>>(B, kiso, acc);
    // 5: i=0 tail term (identity rotation): acc += conv_w(C, kw)
    conv_w_blk<96, WN, true><<<convW192Grid, blk512, 0, stream>>>(C, kw, acc);
    // 6-11: i=1,2 tail terms
    const double a1 = 60.0 * M_PI / 180.0, a2 = 120.0 * M_PI / 180.0;
    const float c1 = (float)cos(a1), s1 = (float)sin(a1);
    const float c2 = (float)cos(a2), s2 = (float)sin(a2);

    rot_fwd_lds<<<rotFGrid, blk256, 0, stream>>>(C, T, c1, s1);
    conv_w_blk<128, SN, false><<<convW256Grid, blk512, 0, stream>>>(T, kw, U);
    rot_bwd_lds<false><<<rotBGrid, blk256, 0, stream>>>(U, acc, nullptr, nullptr, c1, -s1);

    rot_fwd_lds<<<rotFGrid, blk256, 0, stream>>>(C, T, c2, s2);
    conv_w_blk<128, SN, false><<<convW256Grid, blk512, 0, stream>>>(T, kw, U);
    // 12 fused: out = (C + acc + tail2) / norm[c]
    rot_bwd_lds<true><<<rotBGrid, blk256, 0, stream>>>(U, C, acc, norm, c2, -s2);

    (void)in_sizes; (void)n_in; (void)out_size; (void)ws_size;
}